// Round 1
// baseline (194.011 us; speedup 1.0000x reference)
//
#include <hip/hip_runtime.h>

// FlashAttention fwd: B=2, S=2048, H=16, D=64, fp32 in/out, non-causal.
// Block = 256 thr (4 waves), each block: one (b,h) x 128 q-rows.
// Each wave: 32 q-rows. KV tiles of 64 staged in LDS (K swizzled row-major,
// V transposed+swizzled). MFMA 16x16x32 bf16. Online softmax in log2 domain.

#define S_  2048
#define HH  16
#define DD  64
#define QT  128
#define KT  64

typedef __attribute__((ext_vector_type(8))) short short8;
typedef __attribute__((ext_vector_type(4))) float f32x4;

__device__ __forceinline__ unsigned short f2bf(float f) {
    unsigned int u = __float_as_uint(f);
    u += 0x7fffu + ((u >> 16) & 1u);   // RNE
    return (unsigned short)(u >> 16);
}

__device__ __forceinline__ f32x4 mfma16(short8 a, short8 b, f32x4 c) {
    return __builtin_amdgcn_mfma_f32_16x16x32_bf16(a, b, c, 0, 0, 0);
}

__global__ __launch_bounds__(256, 2)
void fattn_kernel(const float* __restrict__ q, const float* __restrict__ k,
                  const float* __restrict__ v, float* __restrict__ out) {
    // LDS: K tile [64][64] bf16 swizzled, V^T tile [64][64] bf16 swizzled,
    // per-wave P buffer [32][64] bf16 swizzled.
    __shared__ short lk[KT * DD];
    __shared__ short lv[DD * KT];
    __shared__ short lp[4][32 * KT];

    const int tid  = threadIdx.x;
    const int lane = tid & 63;
    const int w    = tid >> 6;     // wave 0..3
    const int g    = lane >> 4;    // 16-lane group 0..3
    const int r16  = lane & 15;

    const int bid = blockIdx.x;
    const int qt  = bid & 15;            // 16 q-tiles
    const int bh  = bid >> 4;
    const int h   = bh & 15;
    const int b   = bh >> 4;
    const int q0  = qt * QT;

    // scale = D^-0.5 = 0.125, folded with log2(e) so softmax uses exp2
    const float sc = 0.125f * 1.4426950408889634f;

    // ---- Load Q fragments (A-layout: row = r16, k = kc*32 + 8*g + i) ----
    short8 qf[2][2];
    for (int mt = 0; mt < 2; ++mt) {
        const int qrow = q0 + w * 32 + mt * 16 + r16;
        const float* qp = q + ((size_t)(b * S_ + qrow)) * (HH * DD) + h * DD;
        for (int kc = 0; kc < 2; ++kc) {
            const float4* p4 = reinterpret_cast<const float4*>(qp + kc * 32 + g * 8);
            float4 a = p4[0], bb = p4[1];
            union { short8 s; unsigned short us[8]; } u;
            u.us[0] = f2bf(a.x * sc);  u.us[1] = f2bf(a.y * sc);
            u.us[2] = f2bf(a.z * sc);  u.us[3] = f2bf(a.w * sc);
            u.us[4] = f2bf(bb.x * sc); u.us[5] = f2bf(bb.y * sc);
            u.us[6] = f2bf(bb.z * sc); u.us[7] = f2bf(bb.w * sc);
            qf[mt][kc] = u.s;
        }
    }

    f32x4 o[2][4];
    float m_run[2][4], l_run[2][4];
    for (int mt = 0; mt < 2; ++mt)
        for (int j = 0; j < 4; ++j) {
            m_run[mt][j] = -1e30f; l_run[mt][j] = 0.f;
            for (int dt = 0; dt < 4; ++dt) o[mt][dt][j] = 0.f;
        }

    const float* kbase = k + ((size_t)(b * S_)) * (HH * DD) + h * DD;
    const float* vbase = v + ((size_t)(b * S_)) * (HH * DD) + h * DD;

    for (int t = 0; t < S_ / KT; ++t) {
        __syncthreads();   // previous tile's compute done before overwrite
        // ---- Stage K (swizzled) and V^T (transposed, swizzled) ----
        // wave w: rows = lane (0..63), 16B chunks c = w and w+4
        for (int c = w; c < 8; c += 4) {
            const float* kg = kbase + (size_t)(t * KT + lane) * (HH * DD) + c * 8;
            const float4* kp4 = reinterpret_cast<const float4*>(kg);
            float4 kx = kp4[0], ky = kp4[1];
            union { short8 s; unsigned short us[8]; } uk;
            uk.us[0] = f2bf(kx.x); uk.us[1] = f2bf(kx.y);
            uk.us[2] = f2bf(kx.z); uk.us[3] = f2bf(kx.w);
            uk.us[4] = f2bf(ky.x); uk.us[5] = f2bf(ky.y);
            uk.us[6] = f2bf(ky.z); uk.us[7] = f2bf(ky.w);
            *(short8*)&lk[lane * DD + ((c ^ (lane & 7)) * 8)] = uk.s;

            const float* vg = vbase + (size_t)(t * KT + lane) * (HH * DD) + c * 8;
            const float4* vp4 = reinterpret_cast<const float4*>(vg);
            float4 vx = vp4[0], vy = vp4[1];
            float vv[8] = {vx.x, vx.y, vx.z, vx.w, vy.x, vy.y, vy.z, vy.w};
            #pragma unroll
            for (int i = 0; i < 8; ++i) {
                const int d = c * 8 + i;  // Vt row = d, col = lane (kv)
                lv[d * KT + (((lane >> 3) ^ (d & 7)) * 8) + (lane & 7)] =
                    (short)f2bf(vv[i]);
            }
        }
        __syncthreads();

        // ---- S = Q K^T (per wave: 32 x 64 scores) ----
        f32x4 s_[2][4];
        for (int mt = 0; mt < 2; ++mt)
            for (int nt = 0; nt < 4; ++nt)
                for (int j = 0; j < 4; ++j) s_[mt][nt][j] = 0.f;
        for (int nt = 0; nt < 4; ++nt) {
            const int row = nt * 16 + r16;   // kv row
            for (int kc = 0; kc < 2; ++kc) {
                short8 bf = *(const short8*)&lk[row * DD + (((kc * 4 + g) ^ (row & 7)) * 8)];
                s_[0][nt] = mfma16(qf[0][kc], bf, s_[0][nt]);
                s_[1][nt] = mfma16(qf[1][kc], bf, s_[1][nt]);
            }
        }

        // ---- Online softmax (rows = 4*g + j within each 16-row tile) ----
        for (int mt = 0; mt < 2; ++mt) {
            float corr[4];
            #pragma unroll
            for (int j = 0; j < 4; ++j) {
                float rm = fmaxf(fmaxf(s_[mt][0][j], s_[mt][1][j]),
                                 fmaxf(s_[mt][2][j], s_[mt][3][j]));
                rm = fmaxf(rm, __shfl_xor(rm, 1));
                rm = fmaxf(rm, __shfl_xor(rm, 2));
                rm = fmaxf(rm, __shfl_xor(rm, 4));
                rm = fmaxf(rm, __shfl_xor(rm, 8));
                const float mn = fmaxf(m_run[mt][j], rm);
                corr[j] = exp2f(m_run[mt][j] - mn);
                m_run[mt][j] = mn;
            }
            float rs[4] = {0.f, 0.f, 0.f, 0.f};
            for (int nt = 0; nt < 4; ++nt) {
                #pragma unroll
                for (int j = 0; j < 4; ++j) {
                    const float pf = exp2f(s_[mt][nt][j] - m_run[mt][j]);
                    rs[j] += pf;
                    const int row = mt * 16 + 4 * g + j;
                    const int col = nt * 16 + r16;
                    lp[w][row * KT + (((col >> 3) ^ (row & 7)) * 8) + (col & 7)] =
                        (short)f2bf(pf);
                }
            }
            #pragma unroll
            for (int j = 0; j < 4; ++j) {
                rs[j] += __shfl_xor(rs[j], 1);
                rs[j] += __shfl_xor(rs[j], 2);
                rs[j] += __shfl_xor(rs[j], 4);
                rs[j] += __shfl_xor(rs[j], 8);
                l_run[mt][j] = l_run[mt][j] * corr[j] + rs[j];
                for (int dt = 0; dt < 4; ++dt) o[mt][dt][j] *= corr[j];
            }
        }

        // ---- O += P V ----
        for (int kc = 0; kc < 2; ++kc) {
            short8 pa[2];
            #pragma unroll
            for (int mt = 0; mt < 2; ++mt) {
                const int row = mt * 16 + r16;
                pa[mt] = *(const short8*)&lp[w][row * KT + (((kc * 4 + g) ^ (row & 7)) * 8)];
            }
            for (int dt = 0; dt < 4; ++dt) {
                const int drow = dt * 16 + r16;   // d column
                short8 bv = *(const short8*)&lv[drow * KT + (((kc * 4 + g) ^ (drow & 7)) * 8)];
                o[0][dt] = mfma16(pa[0], bv, o[0][dt]);
                o[1][dt] = mfma16(pa[1], bv, o[1][dt]);
            }
        }
    }

    // ---- Epilogue: O / l ----
    for (int mt = 0; mt < 2; ++mt) {
        #pragma unroll
        for (int j = 0; j < 4; ++j) {
            const float inv = 1.0f / l_run[mt][j];
            const int qrow = q0 + w * 32 + mt * 16 + 4 * g + j;
            float* op = out + ((size_t)(b * S_ + qrow)) * (HH * DD) + h * DD;
            for (int dt = 0; dt < 4; ++dt)
                op[dt * 16 + r16] = o[mt][dt][j] * inv;
        }
    }
}

extern "C" void kernel_launch(void* const* d_in, const int* in_sizes, int n_in,
                              void* d_out, int out_size, void* d_ws, size_t ws_size,
                              hipStream_t stream) {
    const float* q = (const float*)d_in[0];
    const float* k = (const float*)d_in[1];
    const float* v = (const float*)d_in[2];
    float* out = (float*)d_out;
    // grid = B * H * (S/QT) = 2 * 16 * 16 = 512
    dim3 grid(512), block(256);
    fattn_kernel<<<grid, block, 0, stream>>>(q, k, v, out);
}

// Round 3
// 108.421 us; speedup vs baseline: 1.7894x; 1.7894x over previous
//
#include <hip/hip_runtime.h>

// FlashAttention fwd: B=2, S=2048, H=16, D=64, fp32 in/out, non-causal.
// Swapped-QK^T structure, all-verified mechanisms:
//   S^T = K . Q^T  (32x32x16 bf16 MFMA) -> P lane-local (lane c = one q-row)
//   softmax fully in-register (1 shfl_xor(32) per reduce), defer-max THR=8
//   P -> per-wave LDS buffer [32][64] (8x ds_write_b64), re-read as B-frags
//   V staged transposed V^T[d][kv] (R0-verified swizzle), A-frags ds_read_b128
//   O^T = V^T . P^T

#define S_  2048
#define HH  16
#define DD  64
#define QT  128
#define KT  64
#define SR  1024   // H*D floats per token row

typedef __attribute__((ext_vector_type(8)))  short short8;
typedef __attribute__((ext_vector_type(16))) float f32x16;
typedef __attribute__((ext_vector_type(2)))  unsigned uint2v;

__device__ __forceinline__ unsigned short f2bf(float f) {
    unsigned int u = __float_as_uint(f);
    u += 0x7fffu + ((u >> 16) & 1u);   // RNE
    return (unsigned short)(u >> 16);
}

__device__ __forceinline__ unsigned pkbf(float lo, float hi) {
    unsigned r;
    asm("v_cvt_pk_bf16_f32 %0, %1, %2" : "=v"(r) : "v"(lo), "v"(hi));
    return r;
}

__device__ __forceinline__ short8 cvt8(float4 a, float4 b) {
    union { unsigned u[4]; short8 v; } r;
    r.u[0] = pkbf(a.x, a.y); r.u[1] = pkbf(a.z, a.w);
    r.u[2] = pkbf(b.x, b.y); r.u[3] = pkbf(b.z, b.w);
    return r.v;
}

__device__ __forceinline__ f32x16 mfma32(short8 a, short8 b, f32x16 c) {
    return __builtin_amdgcn_mfma_f32_32x32x16_bf16(a, b, c, 0, 0, 0);
}

__global__ __launch_bounds__(256, 2)
void fattn_kernel(const float* __restrict__ q, const float* __restrict__ k,
                  const float* __restrict__ v, float* __restrict__ out) {
    __shared__ short lk[KT * DD];      // K[kv][d]   bf16, 16B-chunk XOR swizzle (8 KB)
    __shared__ short lvT[DD * KT];     // V^T[d][kv] bf16, 8-granule XOR swizzle (8 KB)
    __shared__ short lp[4][32 * KT];   // P[q][kv]   bf16 per wave, swizzled (16 KB)

    const int tid  = threadIdx.x;
    const int lane = tid & 63;
    const int w    = tid >> 6;       // wave 0..3
    const int c    = lane & 31;      // q index within wave tile / matrix col
    const int hi   = lane >> 5;      // k-half selector

    const int bid = blockIdx.x;
    const int qt  = bid & 15;
    const int h   = (bid >> 4) & 15;
    const int b   = bid >> 8;

    const int qrow = qt * QT + w * 32 + c;
    const float sc = 0.125f * 1.4426950408889634f;  // D^-1/2 * log2(e)

    // ---- Q B-fragments: qf[kc][i] = Q[qrow][kc*16 + hi*8 + i] * sc ----
    short8 qf[4];
    {
        const float* qp = q + (size_t)(b * S_ + qrow) * SR + h * DD;
        #pragma unroll
        for (int kc = 0; kc < 4; ++kc) {
            const int d0 = kc * 16 + hi * 8;
            float4 a = *(const float4*)(qp + d0);
            float4 bb = *(const float4*)(qp + d0 + 4);
            a.x *= sc; a.y *= sc; a.z *= sc; a.w *= sc;
            bb.x *= sc; bb.y *= sc; bb.z *= sc; bb.w *= sc;
            qf[kc] = cvt8(a, bb);
        }
    }

    f32x16 o0, o1;
    #pragma unroll
    for (int i = 0; i < 16; ++i) { o0[i] = 0.f; o1[i] = 0.f; }
    float m_run = -1e30f, l_run = 0.f;

    const float* kb = k + (size_t)b * S_ * SR + h * DD;
    const float* vb = v + (size_t)b * S_ * SR + h * DD;

    for (int t = 0; t < S_ / KT; ++t) {
        __syncthreads();   // previous tile's LDS reads done before overwrite
        // ---- Stage K (swizzled rows) + V^T (transposed, swizzled) ----
        // R0-verified pattern: row = lane (kv 0..63), 16B chunks cc = w, w+4
        for (int cc = w; cc < 8; cc += 4) {
            const size_t gro = (size_t)(t * KT + lane) * SR + cc * 8;
            const float4* kp = (const float4*)(kb + gro);
            float4 k0 = kp[0], k1 = kp[1];
            *(short8*)&lk[lane * 64 + ((cc ^ (lane & 7)) * 8)] = cvt8(k0, k1);

            const float4* vp = (const float4*)(vb + gro);
            float4 v0 = vp[0], v1 = vp[1];
            float vv[8] = {v0.x, v0.y, v0.z, v0.w, v1.x, v1.y, v1.z, v1.w};
            #pragma unroll
            for (int i = 0; i < 8; ++i) {
                const int d = cc * 8 + i;   // V^T row = d, col = kv = lane
                lvT[d * 64 + (((lane >> 3) ^ (d & 7)) * 8) + (lane & 7)] =
                    (short)f2bf(vv[i]);
            }
        }
        __syncthreads();

        // ---- S^T = K . Q^T : lane holds S[q=c][kv=(reg&3)+8*(reg>>2)+4*hi (+32 for s1)] ----
        f32x16 s0, s1;
        #pragma unroll
        for (int i = 0; i < 16; ++i) { s0[i] = 0.f; s1[i] = 0.f; }
        #pragma unroll
        for (int kc = 0; kc < 4; ++kc) {
            const int ch = 2 * kc + hi;
            short8 kf0 = *(const short8*)&lk[c * 64 + ((ch ^ (c & 7)) * 8)];
            short8 kf1 = *(const short8*)&lk[(32 + c) * 64 + ((ch ^ (c & 7)) * 8)];
            s0 = mfma32(kf0, qf[kc], s0);
            s1 = mfma32(kf1, qf[kc], s1);
        }

        // ---- Online softmax (log2 domain), defer-max THR=8 ----
        float pmax = s0[0];
        #pragma unroll
        for (int i = 1; i < 16; ++i) pmax = fmaxf(pmax, s0[i]);
        #pragma unroll
        for (int i = 0; i < 16; ++i) pmax = fmaxf(pmax, s1[i]);
        pmax = fmaxf(pmax, __shfl_xor(pmax, 32));

        if (__ballot(pmax > m_run + 8.0f)) {
            const float mn = fmaxf(m_run, pmax);
            const float corr = exp2f(m_run - mn);
            m_run = mn;
            l_run *= corr;
            #pragma unroll
            for (int i = 0; i < 16; ++i) { o0[i] *= corr; o1[i] *= corr; }
        }

        float p0[16], p1[16];
        float rs = 0.f;
        #pragma unroll
        for (int i = 0; i < 16; ++i) { p0[i] = exp2f(s0[i] - m_run); rs += p0[i]; }
        #pragma unroll
        for (int i = 0; i < 16; ++i) { p1[i] = exp2f(s1[i] - m_run); rs += p1[i]; }
        rs += __shfl_xor(rs, 32);
        l_run += rs;

        // ---- Pack P pairs and store to per-wave LDS [q=c][kv], swizzled ----
        // reg 4sp+j holds kv = j + 8*sp + 4*hi (s0) / +32 (s1): each uint2v
        // covers kv 8*s8+4*hi .. +3 -> granule s8 (16B = kv 8*s8..+7), half hi.
        #pragma unroll
        for (int sp = 0; sp < 4; ++sp) {
            uint2v w0;
            w0[0] = pkbf(p0[4 * sp + 0], p0[4 * sp + 1]);
            w0[1] = pkbf(p0[4 * sp + 2], p0[4 * sp + 3]);
            *(uint2v*)&lp[w][c * 64 + ((sp ^ (c & 7)) * 8) + hi * 4] = w0;
            uint2v w1;
            w1[0] = pkbf(p1[4 * sp + 0], p1[4 * sp + 1]);
            w1[1] = pkbf(p1[4 * sp + 2], p1[4 * sp + 3]);
            *(uint2v*)&lp[w][c * 64 + (((4 + sp) ^ (c & 7)) * 8) + hi * 4] = w1;
        }

        // ---- O^T += V^T . P^T  (A = V^T rows d=c / 32+c; B = P^T col q=c) ----
        #pragma unroll
        for (int kc = 0; kc < 4; ++kc) {
            const int gsel = ((2 * kc + hi) ^ (c & 7)) * 8;
            short8 pa  = *(const short8*)&lp[w][c * 64 + gsel];
            short8 va0 = *(const short8*)&lvT[c * 64 + gsel];
            short8 va1 = *(const short8*)&lvT[(32 + c) * 64 + gsel];
            o0 = mfma32(va0, pa, o0);
            o1 = mfma32(va1, pa, o1);
        }
    }

    // ---- Epilogue: O[q=c][d = 8*sp + 4*hi + j (+32 for o1)] / l ----
    const float inv = 1.0f / l_run;
    float* orow = out + (size_t)(b * S_ + qrow) * SR + h * DD;
    #pragma unroll
    for (int sp = 0; sp < 4; ++sp) {
        float4 st0, st1;
        st0.x = o0[4 * sp + 0] * inv; st0.y = o0[4 * sp + 1] * inv;
        st0.z = o0[4 * sp + 2] * inv; st0.w = o0[4 * sp + 3] * inv;
        st1.x = o1[4 * sp + 0] * inv; st1.y = o1[4 * sp + 1] * inv;
        st1.z = o1[4 * sp + 2] * inv; st1.w = o1[4 * sp + 3] * inv;
        *(float4*)(orow + 8 * sp + 4 * hi)      = st0;
        *(float4*)(orow + 32 + 8 * sp + 4 * hi) = st1;
    }
}

extern "C" void kernel_launch(void* const* d_in, const int* in_sizes, int n_in,
                              void* d_out, int out_size, void* d_ws, size_t ws_size,
                              hipStream_t stream) {
    const float* q = (const float*)d_in[0];
    const float* k = (const float*)d_in[1];
    const float* v = (const float*)d_in[2];
    float* out = (float*)d_out;
    dim3 grid(512), block(256);   // B*H*(S/QT) = 2*16*16
    fattn_kernel<<<grid, block, 0, stream>>>(q, k, v, out);
}

// Round 4
// 90.276 us; speedup vs baseline: 2.1491x; 1.2010x over previous
//
#include <hip/hip_runtime.h>

// FlashAttention fwd: B=2, S=2048, H=16, D=64, fp32 in/out, non-causal.
// R3: prep pass converts K->bf16 [b][h][s][d] and V->bf16 transposed
// [b][h][d][s]; attention kernel stages tiles with global_load_lds (16B,
// pre-swizzled global source), double-buffered prefetch, XCD-aware bid
// swizzle. Compute structure = R2-verified swapped-QK^T (32x32 MFMA),
// in-register softmax, P via per-wave LDS round-trip.

#define S_  2048
#define HH  16
#define DD  64
#define QT  128
#define KT  64
#define SR  1024   // H*D floats per token row

typedef __attribute__((ext_vector_type(8)))  short short8;
typedef __attribute__((ext_vector_type(16))) float f32x16;
typedef __attribute__((ext_vector_type(2)))  unsigned uint2v;

__device__ __forceinline__ unsigned short f2bf(float f) {
    unsigned int u = __float_as_uint(f);
    u += 0x7fffu + ((u >> 16) & 1u);   // RNE
    return (unsigned short)(u >> 16);
}

__device__ __forceinline__ unsigned pkbf(float lo, float hi) {
    unsigned r;
    asm("v_cvt_pk_bf16_f32 %0, %1, %2" : "=v"(r) : "v"(lo), "v"(hi));
    return r;
}

__device__ __forceinline__ short8 cvt8(float4 a, float4 b) {
    union { unsigned u[4]; short8 v; } r;
    r.u[0] = pkbf(a.x, a.y); r.u[1] = pkbf(a.z, a.w);
    r.u[2] = pkbf(b.x, b.y); r.u[3] = pkbf(b.z, b.w);
    return r.v;
}

__device__ __forceinline__ f32x16 mfma32(short8 a, short8 b, f32x16 c) {
    return __builtin_amdgcn_mfma_f32_32x32x16_bf16(a, b, c, 0, 0, 0);
}

__device__ __forceinline__ void gload16(const void* g, void* l) {
    __builtin_amdgcn_global_load_lds(
        (const __attribute__((address_space(1))) void*)g,
        (__attribute__((address_space(3))) void*)l, 16, 0, 0);
}

// ---------------- prep kernels ----------------

// K [b][s][h*64+d] fp32  ->  Kb [b][h][s][d] bf16
__global__ __launch_bounds__(256)
void prep_k(const float* __restrict__ k, short* __restrict__ kb) {
    const int gid = blockIdx.x * 256 + threadIdx.x;   // 524288 total
    const int d0 = (gid & 7) * 8;
    const int s  = (gid >> 3) & (S_ - 1);
    const int h  = (gid >> 14) & (HH - 1);
    const int b  = gid >> 18;
    const float* src = k + ((size_t)(b * S_ + s) * SR + h * DD + d0);
    float4 a = *(const float4*)src, bb = *(const float4*)(src + 4);
    *(short8*)&kb[((size_t)(b * HH + h) * S_ + s) * DD + d0] = cvt8(a, bb);
}

// V [b][s][h*64+d] fp32  ->  VTb [b][h][d][s] bf16  (transpose via LDS)
__global__ __launch_bounds__(256)
void prep_vt(const float* __restrict__ v, short* __restrict__ vt) {
    __shared__ short lt[KT][72];   // +8 pad
    const int t = blockIdx.x & 31;
    const int h = (blockIdx.x >> 5) & 15;
    const int b = blockIdx.x >> 9;
    const int tid = threadIdx.x;
    const int c8 = tid & 7, r0 = tid >> 3;
    #pragma unroll
    for (int rr = 0; rr < 2; ++rr) {
        const int row = r0 + rr * 32;   // kv within tile
        const float* src = v + ((size_t)(b * S_ + t * KT + row) * SR + h * DD + c8 * 8);
        float4 a = *(const float4*)src, bb = *(const float4*)(src + 4);
        *(short8*)&lt[row][c8 * 8] = cvt8(a, bb);
    }
    __syncthreads();
    const int d = tid >> 2, q4 = tid & 3;
    short tmp[16];
    #pragma unroll
    for (int i = 0; i < 16; ++i) tmp[i] = lt[q4 * 16 + i][d];
    short8* dst = (short8*)&vt[((size_t)(b * HH + h) * DD + d) * S_ + t * KT + q4 * 16];
    dst[0] = *(short8*)&tmp[0];
    dst[1] = *(short8*)&tmp[8];
}

// ---------------- main attention kernel ----------------

__global__ __launch_bounds__(256, 2)
void fattn_main(const float* __restrict__ q, const short* __restrict__ kb,
                const short* __restrict__ vtb, float* __restrict__ out) {
    __shared__ short lk[2][KT * DD];    // K[kv][d], granule g holds chunk g^(kv&7)
    __shared__ short lvT[2][DD * KT];   // V^T[d][kv], granule g holds kv-chunk g^(d&7)
    __shared__ short lp[4][32 * KT];    // per-wave P[q][kv], swizzled

    const int tid  = threadIdx.x;
    const int lane = tid & 63;
    const int w    = tid >> 6;
    const int c    = lane & 31;
    const int hi   = lane >> 5;

    // XCD swizzle: 512 blocks = 8 XCDs x 64; groups the 16 q-tiles of one
    // (b,h) (which share K/V) onto one XCD for L2 reuse.
    const int bid0 = blockIdx.x;
    const int bid  = ((bid0 & 7) << 6) | (bid0 >> 3);
    const int qt  = bid & 15;
    const int h   = (bid >> 4) & 15;
    const int b   = bid >> 8;
    const int bh  = b * HH + h;

    const int qrow = qt * QT + w * 32 + c;
    const float sc = 0.125f * 1.4426950408889634f;  // D^-1/2 * log2(e)

    // ---- Q B-fragments: qf[kc][i] = Q[qrow][kc*16 + hi*8 + i] * sc ----
    short8 qf[4];
    {
        const float* qp = q + (size_t)(b * S_ + qrow) * SR + h * DD;
        #pragma unroll
        for (int kc = 0; kc < 4; ++kc) {
            const int d0 = kc * 16 + hi * 8;
            float4 a = *(const float4*)(qp + d0);
            float4 bb = *(const float4*)(qp + d0 + 4);
            a.x *= sc; a.y *= sc; a.z *= sc; a.w *= sc;
            bb.x *= sc; bb.y *= sc; bb.z *= sc; bb.w *= sc;
            qf[kc] = cvt8(a, bb);
        }
    }

    f32x16 o0, o1;
    #pragma unroll
    for (int i = 0; i < 16; ++i) { o0[i] = 0.f; o1[i] = 0.f; }
    float m_run = -1e30f, l_run = 0.f;

    const short* kbh = kb  + (size_t)bh * S_ * DD;
    const short* vbh = vtb + (size_t)bh * DD * S_;
    const int r8 = lane >> 3;   // row within 8-row section
    const int g8 = lane & 7;    // LDS granule this lane fills

    // stage tile t into buffer bufi: 4 x global_load_lds per wave,
    // global source pre-swizzled so linear LDS == swizzled layout.
    #define STAGE(t_, bufi_)                                                   \
        _Pragma("unroll")                                                      \
        for (int ss = 0; ss < 2; ++ss) {                                       \
            const int sect = 2 * w + ss;                                       \
            const int row  = sect * 8 + r8;                                    \
            gload16(kbh + (size_t)((t_) * KT + row) * DD + ((g8 ^ (row & 7)) * 8), \
                    &lk[bufi_][sect * 512]);                                   \
            gload16(vbh + (size_t)row * S_ + (t_) * KT + ((g8 ^ (row & 7)) * 8),   \
                    &lvT[bufi_][sect * 512]);                                  \
        }

    STAGE(0, 0);

    for (int t = 0; t < S_ / KT; ++t) {
        const int cur = t & 1;
        __syncthreads();   // drains tile-t loads; prev tile's LDS reads done
        if (t + 1 < S_ / KT) { STAGE(t + 1, cur ^ 1); }

        // ---- S^T = K . Q^T : lane holds S[q=c][kv=(r&3)+8*(r>>2)+4*hi (+32)] ----
        f32x16 s0, s1;
        #pragma unroll
        for (int i = 0; i < 16; ++i) { s0[i] = 0.f; s1[i] = 0.f; }
        #pragma unroll
        for (int kc = 0; kc < 4; ++kc) {
            const int ch = 2 * kc + hi;
            short8 kf0 = *(const short8*)&lk[cur][c * 64 + ((ch ^ (c & 7)) * 8)];
            short8 kf1 = *(const short8*)&lk[cur][(32 + c) * 64 + ((ch ^ (c & 7)) * 8)];
            s0 = mfma32(kf0, qf[kc], s0);
            s1 = mfma32(kf1, qf[kc], s1);
        }

        // ---- Online softmax (log2 domain), defer-max THR=8 ----
        float pmax = fmaxf(s0[0], s0[1]);
        #pragma unroll
        for (int i = 2; i < 16; ++i) pmax = fmaxf(pmax, s0[i]);
        #pragma unroll
        for (int i = 0; i < 16; ++i) pmax = fmaxf(pmax, s1[i]);
        pmax = fmaxf(pmax, __shfl_xor(pmax, 32));

        if (__ballot(pmax > m_run + 8.0f)) {
            const float mn = fmaxf(m_run, pmax);
            const float corr = exp2f(m_run - mn);
            m_run = mn;
            l_run *= corr;
            #pragma unroll
            for (int i = 0; i < 16; ++i) { o0[i] *= corr; o1[i] *= corr; }
        }

        float p0[16], p1[16];
        float rs = 0.f;
        #pragma unroll
        for (int i = 0; i < 16; ++i) { p0[i] = exp2f(s0[i] - m_run); rs += p0[i]; }
        #pragma unroll
        for (int i = 0; i < 16; ++i) { p1[i] = exp2f(s1[i] - m_run); rs += p1[i]; }
        rs += __shfl_xor(rs, 32);
        l_run += rs;

        // ---- Pack P pairs -> per-wave LDS [q=c][kv], swizzled ----
        #pragma unroll
        for (int sp = 0; sp < 4; ++sp) {
            uint2v w0;
            w0[0] = pkbf(p0[4 * sp + 0], p0[4 * sp + 1]);
            w0[1] = pkbf(p0[4 * sp + 2], p0[4 * sp + 3]);
            *(uint2v*)&lp[w][c * 64 + ((sp ^ (c & 7)) * 8) + hi * 4] = w0;
            uint2v w1;
            w1[0] = pkbf(p1[4 * sp + 0], p1[4 * sp + 1]);
            w1[1] = pkbf(p1[4 * sp + 2], p1[4 * sp + 3]);
            *(uint2v*)&lp[w][c * 64 + (((4 + sp) ^ (c & 7)) * 8) + hi * 4] = w1;
        }

        // ---- O^T += V^T . P^T ----
        #pragma unroll
        for (int kc = 0; kc < 4; ++kc) {
            const int gsel = ((2 * kc + hi) ^ (c & 7)) * 8;
            short8 pa  = *(const short8*)&lp[w][c * 64 + gsel];
            short8 va0 = *(const short8*)&lvT[cur][c * 64 + gsel];
            short8 va1 = *(const short8*)&lvT[cur][(32 + c) * 64 + gsel];
            o0 = mfma32(va0, pa, o0);
            o1 = mfma32(va1, pa, o1);
        }
    }

    // ---- Epilogue ----
    const float inv = 1.0f / l_run;
    float* orow = out + (size_t)(b * S_ + qrow) * SR + h * DD;
    #pragma unroll
    for (int sp = 0; sp < 4; ++sp) {
        float4 st0, st1;
        st0.x = o0[4 * sp + 0] * inv; st0.y = o0[4 * sp + 1] * inv;
        st0.z = o0[4 * sp + 2] * inv; st0.w = o0[4 * sp + 3] * inv;
        st1.x = o1[4 * sp + 0] * inv; st1.y = o1[4 * sp + 1] * inv;
        st1.z = o1[4 * sp + 2] * inv; st1.w = o1[4 * sp + 3] * inv;
        *(float4*)(orow + 8 * sp + 4 * hi)      = st0;
        *(float4*)(orow + 32 + 8 * sp + 4 * hi) = st1;
    }
}

// ---------------- fallback (R2-verified, used if ws too small) ----------------

__global__ __launch_bounds__(256, 2)
void fattn_fb(const float* __restrict__ q, const float* __restrict__ k,
              const float* __restrict__ v, float* __restrict__ out) {
    __shared__ short lk[KT * DD];
    __shared__ short lvT[DD * KT];
    __shared__ short lp[4][32 * KT];

    const int tid  = threadIdx.x;
    const int lane = tid & 63;
    const int w    = tid >> 6;
    const int c    = lane & 31;
    const int hi   = lane >> 5;

    const int bid = blockIdx.x;
    const int qt  = bid & 15;
    const int h   = (bid >> 4) & 15;
    const int b   = bid >> 8;

    const int qrow = qt * QT + w * 32 + c;
    const float sc = 0.125f * 1.4426950408889634f;

    short8 qf[4];
    {
        const float* qp = q + (size_t)(b * S_ + qrow) * SR + h * DD;
        #pragma unroll
        for (int kc = 0; kc < 4; ++kc) {
            const int d0 = kc * 16 + hi * 8;
            float4 a = *(const float4*)(qp + d0);
            float4 bb = *(const float4*)(qp + d0 + 4);
            a.x *= sc; a.y *= sc; a.z *= sc; a.w *= sc;
            bb.x *= sc; bb.y *= sc; bb.z *= sc; bb.w *= sc;
            qf[kc] = cvt8(a, bb);
        }
    }

    f32x16 o0, o1;
    #pragma unroll
    for (int i = 0; i < 16; ++i) { o0[i] = 0.f; o1[i] = 0.f; }
    float m_run = -1e30f, l_run = 0.f;

    const float* kb = k + (size_t)b * S_ * SR + h * DD;
    const float* vb = v + (size_t)b * S_ * SR + h * DD;

    for (int t = 0; t < S_ / KT; ++t) {
        __syncthreads();
        for (int cc = w; cc < 8; cc += 4) {
            const size_t gro = (size_t)(t * KT + lane) * SR + cc * 8;
            const float4* kp = (const float4*)(kb + gro);
            float4 k0 = kp[0], k1 = kp[1];
            *(short8*)&lk[lane * 64 + ((cc ^ (lane & 7)) * 8)] = cvt8(k0, k1);
            const float4* vp = (const float4*)(vb + gro);
            float4 v0 = vp[0], v1 = vp[1];
            float vv[8] = {v0.x, v0.y, v0.z, v0.w, v1.x, v1.y, v1.z, v1.w};
            #pragma unroll
            for (int i = 0; i < 8; ++i) {
                const int d = cc * 8 + i;
                lvT[d * 64 + (((lane >> 3) ^ (d & 7)) * 8) + (lane & 7)] =
                    (short)f2bf(vv[i]);
            }
        }
        __syncthreads();

        f32x16 s0, s1;
        #pragma unroll
        for (int i = 0; i < 16; ++i) { s0[i] = 0.f; s1[i] = 0.f; }
        #pragma unroll
        for (int kc = 0; kc < 4; ++kc) {
            const int ch = 2 * kc + hi;
            short8 kf0 = *(const short8*)&lk[c * 64 + ((ch ^ (c & 7)) * 8)];
            short8 kf1 = *(const short8*)&lk[(32 + c) * 64 + ((ch ^ (c & 7)) * 8)];
            s0 = mfma32(kf0, qf[kc], s0);
            s1 = mfma32(kf1, qf[kc], s1);
        }

        float pmax = fmaxf(s0[0], s0[1]);
        #pragma unroll
        for (int i = 2; i < 16; ++i) pmax = fmaxf(pmax, s0[i]);
        #pragma unroll
        for (int i = 0; i < 16; ++i) pmax = fmaxf(pmax, s1[i]);
        pmax = fmaxf(pmax, __shfl_xor(pmax, 32));

        if (__ballot(pmax > m_run + 8.0f)) {
            const float mn = fmaxf(m_run, pmax);
            const float corr = exp2f(m_run - mn);
            m_run = mn;
            l_run *= corr;
            #pragma unroll
            for (int i = 0; i < 16; ++i) { o0[i] *= corr; o1[i] *= corr; }
        }

        float p0[16], p1[16];
        float rs = 0.f;
        #pragma unroll
        for (int i = 0; i < 16; ++i) { p0[i] = exp2f(s0[i] - m_run); rs += p0[i]; }
        #pragma unroll
        for (int i = 0; i < 16; ++i) { p1[i] = exp2f(s1[i] - m_run); rs += p1[i]; }
        rs += __shfl_xor(rs, 32);
        l_run += rs;

        #pragma unroll
        for (int sp = 0; sp < 4; ++sp) {
            uint2v w0;
            w0[0] = pkbf(p0[4 * sp + 0], p0[4 * sp + 1]);
            w0[1] = pkbf(p0[4 * sp + 2], p0[4 * sp + 3]);
            *(uint2v*)&lp[w][c * 64 + ((sp ^ (c & 7)) * 8) + hi * 4] = w0;
            uint2v w1;
            w1[0] = pkbf(p1[4 * sp + 0], p1[4 * sp + 1]);
            w1[1] = pkbf(p1[4 * sp + 2], p1[4 * sp + 3]);
            *(uint2v*)&lp[w][c * 64 + (((4 + sp) ^ (c & 7)) * 8) + hi * 4] = w1;
        }

        #pragma unroll
        for (int kc = 0; kc < 4; ++kc) {
            const int gsel = ((2 * kc + hi) ^ (c & 7)) * 8;
            short8 pa  = *(const short8*)&lp[w][c * 64 + gsel];
            short8 va0 = *(const short8*)&lvT[c * 64 + gsel];
            short8 va1 = *(const short8*)&lvT[(32 + c) * 64 + gsel];
            o0 = mfma32(va0, pa, o0);
            o1 = mfma32(va1, pa, o1);
        }
    }

    const float inv = 1.0f / l_run;
    float* orow = out + (size_t)(b * S_ + qrow) * SR + h * DD;
    #pragma unroll
    for (int sp = 0; sp < 4; ++sp) {
        float4 st0, st1;
        st0.x = o0[4 * sp + 0] * inv; st0.y = o0[4 * sp + 1] * inv;
        st0.z = o0[4 * sp + 2] * inv; st0.w = o0[4 * sp + 3] * inv;
        st1.x = o1[4 * sp + 0] * inv; st1.y = o1[4 * sp + 1] * inv;
        st1.z = o1[4 * sp + 2] * inv; st1.w = o1[4 * sp + 3] * inv;
        *(float4*)(orow + 8 * sp + 4 * hi)      = st0;
        *(float4*)(orow + 32 + 8 * sp + 4 * hi) = st1;
    }
}

extern "C" void kernel_launch(void* const* d_in, const int* in_sizes, int n_in,
                              void* d_out, int out_size, void* d_ws, size_t ws_size,
                              hipStream_t stream) {
    const float* q = (const float*)d_in[0];
    const float* k = (const float*)d_in[1];
    const float* v = (const float*)d_in[2];
    float* out = (float*)d_out;

    const size_t elems = (size_t)2 * HH * S_ * DD;      // 4.19M bf16 per tensor
    const size_t need  = elems * 2 * sizeof(short);     // Kb + VTb = 16.8 MB
    if (ws_size >= need) {
        short* kbuf  = (short*)d_ws;
        short* vtbuf = kbuf + elems;
        prep_k<<<dim3(2048), dim3(256), 0, stream>>>(k, kbuf);
        prep_vt<<<dim3(1024), dim3(256), 0, stream>>>(v, vtbuf);
        fattn_main<<<dim3(512), dim3(256), 0, stream>>>(q, kbuf, vtbuf, out);
    } else {
        fattn_fb<<<dim3(512), dim3(256), 0, stream>>>(q, k, v, out);
    }
}